// Round 10
// baseline (780.481 us; speedup 1.0000x reference)
//
#include <hip/hip_runtime.h>
#include <math.h>

#define HD 512
#define BB 4
#define TT 128
#define SS 512
#define NBLK 1024

typedef __attribute__((ext_vector_type(8))) short short8;
typedef __attribute__((ext_vector_type(4))) float floatx4;
typedef _Float16 half2_t __attribute__((ext_vector_type(2)));
typedef unsigned short ushort_t;
typedef unsigned int uint_t;

__device__ __forceinline__ float tanh_e(float x) {
    float t = __builtin_amdgcn_rcpf(__expf(2.f * x) + 1.f);
    return fmaf(-2.f, t, 1.f);
}
__device__ __forceinline__ ushort_t f2bf(float x) {      // RNE fp32->bf16
    unsigned int u = __float_as_uint(x);
    u += 0x7fffu + ((u >> 16) & 1u);
    return (ushort_t)(u >> 16);
}

// Two-level grid barrier: 32 sharded counters -> master -> per-block flag broadcast.
// All NBLK blocks are co-resident (launch_bounds guarantees >=4 blocks/CU), so this
// cannot deadlock. Barrier region zeroed by hipMemsetAsync before launch.
__device__ __forceinline__ void grid_barrier(uint_t* cnt, uint_t* master,
                                             uint_t* flags, int gen, int bid) {
    __shared__ int amlast;
    __syncthreads();
    if (threadIdx.x == 0) {
        int last = 0;
        uint_t o = __hip_atomic_fetch_add(&cnt[(gen * 32 + (bid & 31)) * 16], 1u,
                                          __ATOMIC_ACQ_REL, __HIP_MEMORY_SCOPE_AGENT);
        if (o == 31) {   // shard complete (1024/32 = 32 per shard)
            uint_t m = __hip_atomic_fetch_add(&master[gen * 16], 1u,
                                              __ATOMIC_ACQ_REL, __HIP_MEMORY_SCOPE_AGENT);
            last = (m == 31);
        }
        amlast = last;
    }
    __syncthreads();
    if (amlast) {
        __threadfence();
        for (int i = (int)threadIdx.x; i < NBLK; i += 256)
            __hip_atomic_store(&flags[i], (uint_t)(gen + 1), __ATOMIC_RELAXED,
                               __HIP_MEMORY_SCOPE_AGENT);
    } else if (threadIdx.x == 0) {
        while (__hip_atomic_load(&flags[bid], __ATOMIC_ACQUIRE,
                                 __HIP_MEMORY_SCOPE_AGENT) < (uint_t)(gen + 1))
            __builtin_amdgcn_s_sleep(4);
    }
    __syncthreads();
}

#define LDP 40
#define LDA_F 520
#define LDA_B 76

__global__ __launch_bounds__(256, 4) void mega_kernel(
    const float* __restrict__ query, const float* __restrict__ enc,
    const int* __restrict__ lens,
    const float* __restrict__ Ws, const float* __restrict__ Wh,
    const float* __restrict__ Wo, const float* __restrict__ v,
    float* __restrict__ out, uint_t* bar,
    ushort_t* WTs, ushort_t* WTh, ushort_t* WTo,
    ushort_t* encB, float2* tqa, _Float16* peT, _Float16* sp, ushort_t* cq)
{
    __shared__ __attribute__((aligned(16))) unsigned char smem[21504];
    const int bid = blockIdx.x;
    const int tid = threadIdx.x;
    uint_t* cnt    = bar;               // 4 gens x 32 shards x 64B
    uint_t* master = bar + 2048;        // 4 gens x 64B
    uint_t* flags  = bar + 2048 + 64;   // 1024 dwords

    // ================= P0: prep (W transpose, query->cq, enc->encB) =================
    if (bid < 128) {
        const float* src; ushort_t* dst; int K, l;
        if (bid < 32)      { src = Ws; dst = WTs; K = 512;  l = bid;      }
        else if (bid < 64) { src = Wh; dst = WTh; K = 512;  l = bid - 32; }
        else               { src = Wo; dst = WTo; K = 1024; l = bid - 64; }
        const int ktiles = K >> 7;
        const int tk = l & (ktiles - 1), tn = l / ktiles;
        const int k0 = tk * 128, n0 = tn * 64;
        ushort_t (*tile)[136] = (ushort_t (*)[136])smem;
        const int lr  = tid >> 4;
        const int lc4 = (tid & 15) * 4;
        #pragma unroll
        for (int p = 0; p < 8; ++p) {
            const int row = p * 16 + lr;
            float4 s = *(const float4*)(src + (size_t)(k0 + row) * HD + n0 + lc4);
            tile[lc4 + 0][row] = f2bf(s.x);
            tile[lc4 + 1][row] = f2bf(s.y);
            tile[lc4 + 2][row] = f2bf(s.z);
            tile[lc4 + 3][row] = f2bf(s.w);
        }
        __syncthreads();
        const int n = tid >> 2, kc = (tid & 3) * 32;
        #pragma unroll
        for (int j = 0; j < 4; ++j) {
            uint4 o = *(const uint4*)&tile[n][kc + j * 8];
            *(uint4*)&dst[(size_t)(n0 + n) * K + k0 + kc + j * 8] = o;
        }
    } else if (bid < 256) {
        const int idx = ((bid - 128) * 256 + tid) * 8;
        const int m = idx >> 9, h = idx & 511;
        float4 q0 = *(const float4*)(query + (size_t)m * HD + h);
        float4 q1 = *(const float4*)(query + (size_t)m * HD + h + 4);
        uint4 o;
        o.x = (uint_t)f2bf(q0.x) | ((uint_t)f2bf(q0.y) << 16);
        o.y = (uint_t)f2bf(q0.z) | ((uint_t)f2bf(q0.w) << 16);
        o.z = (uint_t)f2bf(q1.x) | ((uint_t)f2bf(q1.y) << 16);
        o.w = (uint_t)f2bf(q1.z) | ((uint_t)f2bf(q1.w) << 16);
        *(uint4*)&cq[(size_t)m * 1024 + 512 + h] = o;
    } else if (bid < 768) {
        const size_t idx = ((size_t)(bid - 256) * 256 + tid) * 8;
        float4 e0 = *(const float4*)(enc + idx);
        float4 e1 = *(const float4*)(enc + idx + 4);
        uint4 o;
        o.x = (uint_t)f2bf(e0.x) | ((uint_t)f2bf(e0.y) << 16);
        o.y = (uint_t)f2bf(e0.z) | ((uint_t)f2bf(e0.w) << 16);
        o.z = (uint_t)f2bf(e1.x) | ((uint_t)f2bf(e1.y) << 16);
        o.w = (uint_t)f2bf(e1.z) | ((uint_t)f2bf(e1.w) << 16);
        *(uint4*)&encB[idx] = o;
    }
    grid_barrier(cnt, master, flags, 0, bid);

    // ================= P1: MFMA proj (320 active blocks) =================
    if (bid < 320) {
        const int bm = bid >> 3, bn = bid & 7;
        const bool isQ = (bm < 8);
        const ushort_t* A = isQ ? (cq + 512) : encB;
        const int lda = isQ ? 1024 : 512;
        const ushort_t* WT = isQ ? WTs : WTh;
        const int m0 = (isQ ? bm : bm - 8) * 64;
        const int n0 = bn * 64;

        ushort_t* As = (ushort_t*)smem;        // [m][k] 64*LDP
        ushort_t* Bs = As + 64 * LDP;          // [n][k]

        const int lane = tid & 63, w = tid >> 6;
        const int quad = lane >> 4, lrow = lane & 15;
        const int mw = (w & 1) * 32, nw = (w >> 1) * 32;
        const int ar = tid >> 2;
        const int ac = (tid & 3) * 8;

        floatx4 zero = {0.f, 0.f, 0.f, 0.f};
        floatx4 acc[2][2] = {{zero, zero}, {zero, zero}};

        uint4 ald = *(const uint4*)&A[(size_t)(m0 + ar) * lda + ac];
        uint4 bld = *(const uint4*)&WT[(size_t)(n0 + ar) * HD + ac];

        for (int k0 = 0; k0 < HD; k0 += 32) {
            __syncthreads();
            *(uint4*)&As[ar * LDP + ac] = ald;
            *(uint4*)&Bs[ar * LDP + ac] = bld;
            __syncthreads();
            if (k0 + 32 < HD) {
                ald = *(const uint4*)&A[(size_t)(m0 + ar) * lda + k0 + 32 + ac];
                bld = *(const uint4*)&WT[(size_t)(n0 + ar) * HD + k0 + 32 + ac];
            }
            short8 af[2], bf[2];
            #pragma unroll
            for (int i = 0; i < 2; ++i)
                af[i] = *(const short8*)&As[(mw + i * 16 + lrow) * LDP + quad * 8];
            #pragma unroll
            for (int j = 0; j < 2; ++j)
                bf[j] = *(const short8*)&Bs[(nw + j * 16 + lrow) * LDP + quad * 8];
            #pragma unroll
            for (int i = 0; i < 2; ++i)
                #pragma unroll
                for (int j = 0; j < 2; ++j)
                    acc[i][j] = __builtin_amdgcn_mfma_f32_16x16x32_bf16(af[i], bf[j], acc[i][j], 0, 0, 0);
        }

        if (isQ) {
            #pragma unroll
            for (int j = 0; j < 2; ++j) {
                const int col = n0 + nw + j * 16 + lrow;
                const float vj = v[col];
                #pragma unroll
                for (int i = 0; i < 2; ++i)
                    #pragma unroll
                    for (int r = 0; r < 4; ++r) {
                        const int row = m0 + mw + i * 16 + quad * 4 + r;
                        float tq = tanh_e(acc[i][j][r]);
                        float2 o; o.x = tq; o.y = vj * tq;
                        tqa[(size_t)row * HD + col] = o;
                    }
            }
        } else {
            #pragma unroll
            for (int i = 0; i < 2; ++i)
                #pragma unroll
                for (int j = 0; j < 2; ++j) {
                    const int gm = m0 + mw + i * 16 + quad * 4;
                    const int b = gm >> 9, s = gm & 511;
                    const int col = n0 + nw + j * 16 + lrow;
                    _Float16 t0 = (_Float16)tanh_e(acc[i][j][0]);
                    _Float16 t1 = (_Float16)tanh_e(acc[i][j][1]);
                    _Float16 t2 = (_Float16)tanh_e(acc[i][j][2]);
                    _Float16 t3 = (_Float16)tanh_e(acc[i][j][3]);
                    ushort4 o;
                    o.x = *(ushort_t*)&t0; o.y = *(ushort_t*)&t1;
                    o.z = *(ushort_t*)&t2; o.w = *(ushort_t*)&t3;
                    *(ushort4*)((ushort_t*)peT + ((size_t)b * HD + col) * SS + s) = o;
                }
        }
    }
    grid_barrier(cnt, master, flags, 1, bid);

    // ================= P2: partial scores (all 1024 blocks, 2 half-units each) =========
    {
        const int u = bid * 2 + (tid >> 7);     // 0..2047
        const int ltid = tid & 127;
        const int bt = u >> 2;
        const int hq = u & 3;
        const int b = bt >> 7;
        const int h0 = hq * 128;
        const int len = lens[b];
        const int s0 = ltid * 4;
        if (s0 < len) {
            const float2* qa = tqa + (size_t)bt * HD + h0;
            const float* vp = v + h0;
            const ushort_t* col = (const ushort_t*)peT + ((size_t)b * HD + h0) * SS + s0;
            float acc[4] = {0.f, 0.f, 0.f, 0.f};
            #pragma unroll 4
            for (int h = 0; h < 128; h += 2) {
                uint2 pA = *(const uint2*)(col + (size_t)h * SS);
                uint2 pB = *(const uint2*)(col + (size_t)(h + 1) * SS);
                const float2 qA = qa[h], qB = qa[h + 1];
                const float vA = vp[h], vB = vp[h + 1];
                half2_t a01 = *(half2_t*)&pA.x, a23 = *(half2_t*)&pA.y;
                half2_t b01 = *(half2_t*)&pB.x, b23 = *(half2_t*)&pB.y;
                float teA[4] = {(float)a01[0], (float)a01[1], (float)a23[0], (float)a23[1]};
                float teB[4] = {(float)b01[0], (float)b01[1], (float)b23[0], (float)b23[1]};
                #pragma unroll
                for (int s = 0; s < 4; ++s) {
                    float dA = fmaf(qA.x, teA[s], 1.f);
                    float dB = fmaf(qB.x, teB[s], 1.f);
                    float mA = fmaf(vA, teA[s], qA.y);
                    float mB = fmaf(vB, teB[s], qB.y);
                    float num = mA * dB;
                    num = fmaf(mB, dA, num);
                    acc[s] = fmaf(num, __builtin_amdgcn_rcpf(dA * dB), acc[s]);
                }
            }
            _Float16 f0 = (_Float16)acc[0], f1 = (_Float16)acc[1];
            _Float16 f2 = (_Float16)acc[2], f3 = (_Float16)acc[3];
            uint2 pk;
            pk.x = (uint_t)*(ushort_t*)&f0 | ((uint_t)*(ushort_t*)&f1 << 16);
            pk.y = (uint_t)*(ushort_t*)&f2 | ((uint_t)*(ushort_t*)&f3 << 16);
            *(uint2*)(sp + ((size_t)hq * (BB * TT) + bt) * SS + s0) = pk;
        }
    }
    grid_barrier(cnt, master, flags, 2, bid);

    // ================= P3: fused softmax + ctx MFMA (256 active blocks) ==============
    if (bid < 256) {
        const int b = bid >> 6;
        const int t0 = ((bid >> 3) & 7) * 16;
        const int h0 = (bid & 7) * 64;
        ushort_t* sA = (ushort_t*)smem;          // [t][s] 16*LDA_F
        ushort_t* sB = sA + 16 * LDA_F;          // [s][h] 32*LDA_B
        const int lane = tid & 63, w = tid >> 6;
        const int quad = lane >> 4, lrow = lane & 15;
        const int nw = w * 16;
        const int len = lens[b];

        const int ar  = tid >> 4;
        const int si2 = (tid & 15) * 2;
        const int br  = tid >> 3;
        const int bc8 = (tid & 7) * 8;

        const size_t ST = (size_t)BB * TT * SS;
        const ushort_t* sprow = (const ushort_t*)sp + (size_t)(b * TT + t0 + ar) * SS;
        float sc[32];
        float m = -INFINITY;
        #pragma unroll
        for (int j = 0; j < 16; ++j) {
            const int s = si2 + 32 * j;
            float v0 = -INFINITY, v1 = -INFINITY;
            if (s < len) {
                uint_t p0 = *(const uint_t*)(sprow + s);
                uint_t p1 = *(const uint_t*)(sprow + ST + s);
                uint_t p2 = *(const uint_t*)(sprow + 2 * ST + s);
                uint_t p3 = *(const uint_t*)(sprow + 3 * ST + s);
                half2_t h0v = *(half2_t*)&p0, h1v = *(half2_t*)&p1;
                half2_t h2v = *(half2_t*)&p2, h3v = *(half2_t*)&p3;
                v0 = ((float)h0v[0] + (float)h1v[0]) + ((float)h2v[0] + (float)h3v[0]);
                float a1 = ((float)h0v[1] + (float)h1v[1]) + ((float)h2v[1] + (float)h3v[1]);
                v1 = (s + 1 < len) ? a1 : -INFINITY;
            }
            sc[2 * j] = v0; sc[2 * j + 1] = v1;
            m = fmaxf(m, fmaxf(v0, v1));
        }
        #pragma unroll
        for (int off = 1; off < 16; off <<= 1) m = fmaxf(m, __shfl_xor(m, off, 64));
        float l = 0.f;
        #pragma unroll
        for (int j = 0; j < 32; ++j) { sc[j] = __expf(sc[j] - m); l += sc[j]; }
        #pragma unroll
        for (int off = 1; off < 16; off <<= 1) l += __shfl_xor(l, off, 64);
        const float inv = __builtin_amdgcn_rcpf(l);
        #pragma unroll
        for (int j = 0; j < 16; ++j) {
            uint_t pk = (uint_t)f2bf(sc[2 * j] * inv) | ((uint_t)f2bf(sc[2 * j + 1] * inv) << 16);
            *(uint_t*)&sA[ar * LDA_F + si2 + 32 * j] = pk;
        }

        floatx4 acc = {0.f, 0.f, 0.f, 0.f};
        for (int s0 = 0; s0 < len; s0 += 32) {
            __syncthreads();
            {
                uint4 ev = *(const uint4*)&encB[(size_t)(b * SS + s0 + br) * HD + h0 + bc8];
                *(uint4*)&sB[br * LDA_B + bc8] = ev;
            }
            __syncthreads();
            short8 af = *(const short8*)&sA[lrow * LDA_F + s0 + quad * 8];
            short8 bf;
            #pragma unroll
            for (int j = 0; j < 8; ++j)
                bf[j] = (short)sB[(quad * 8 + j) * LDA_B + nw + lrow];
            acc = __builtin_amdgcn_mfma_f32_16x16x32_bf16(af, bf, acc, 0, 0, 0);
        }
        #pragma unroll
        for (int r = 0; r < 4; ++r)
            cq[(size_t)(b * TT + t0 + quad * 4 + r) * 1024 + h0 + nw + lrow] = f2bf(acc[r]);
    }
    grid_barrier(cnt, master, flags, 3, bid);

    // ================= P4: out = tanh(cq @ WTo^T) (256 active blocks) ================
    if (bid < 256) {
        const int m0 = (bid >> 4) * 32;
        const int n0 = (bid & 15) * 32;
        ushort_t* As = (ushort_t*)smem;
        ushort_t* Bs = As + 32 * LDP;

        const int lane = tid & 63, w = tid >> 6;
        const int quad = lane >> 4, lrow = lane & 15;
        const int mw = (w & 1) * 16, nw = (w >> 1) * 16;
        const int r8 = tid >> 3, c4 = (tid & 7) * 4;

        floatx4 acc = {0.f, 0.f, 0.f, 0.f};

        uint2 av = *(const uint2*)&cq[(size_t)(m0 + r8) * 1024 + c4];
        uint2 bv = *(const uint2*)&WTo[(size_t)(n0 + r8) * 1024 + c4];

        for (int k0 = 0; k0 < 1024; k0 += 32) {
            __syncthreads();
            *(uint2*)&As[r8 * LDP + c4] = av;
            *(uint2*)&Bs[r8 * LDP + c4] = bv;
            __syncthreads();
            if (k0 + 32 < 1024) {
                av = *(const uint2*)&cq[(size_t)(m0 + r8) * 1024 + k0 + 32 + c4];
                bv = *(const uint2*)&WTo[(size_t)(n0 + r8) * 1024 + k0 + 32 + c4];
            }
            short8 af = *(const short8*)&As[(mw + lrow) * LDP + quad * 8];
            short8 bf = *(const short8*)&Bs[(nw + lrow) * LDP + quad * 8];
            acc = __builtin_amdgcn_mfma_f32_16x16x32_bf16(af, bf, acc, 0, 0, 0);
        }
        #pragma unroll
        for (int r = 0; r < 4; ++r) {
            const int row = m0 + mw + quad * 4 + r;
            const int col = n0 + nw + lrow;
            out[(size_t)row * HD + col] = tanh_e(acc[r]);
        }
    }
}

extern "C" void kernel_launch(void* const* d_in, const int* in_sizes, int n_in,
                              void* d_out, int out_size, void* d_ws, size_t ws_size,
                              hipStream_t stream) {
    (void)in_sizes; (void)n_in; (void)out_size; (void)ws_size;
    const float* query = (const float*)d_in[0];   // (B,T,H)
    const float* enc   = (const float*)d_in[1];   // (B,S,H)
    const int*   lens  = (const int*)d_in[2];     // (B,)
    const float* W_h   = (const float*)d_in[3];   // (H,H)
    const float* W_s   = (const float*)d_in[4];   // (H,H)
    const float* v     = (const float*)d_in[5];   // (H,)
    const float* W_out = (const float*)d_in[6];   // (2H,H)
    float* out = (float*)d_out;

    // workspace layout: [0,16K) barrier state, then data buffers (~11 MB)
    uint_t*   bar   = (uint_t*)d_ws;
    ushort_t* WTs   = (ushort_t*)((char*)d_ws + 16384);         // 512 KB
    ushort_t* WTh   = WTs + (size_t)HD * HD;                    // 512 KB
    ushort_t* WTo   = WTh + (size_t)HD * HD;                    // 1 MB
    ushort_t* encB  = WTo + (size_t)HD * 2 * HD;                // 2 MB (bf16 enc)
    float2*   tqa   = (float2*)(encB + (size_t)BB * SS * HD);   // 2 MB {tanh(pq), v*tanh(pq)}
    _Float16* peT   = (_Float16*)(tqa + (size_t)BB * TT * HD);  // 2 MB fp16 tanh(pe)^T
    _Float16* sp    = peT + (size_t)BB * HD * SS;               // 2 MB fp16 partials
    ushort_t* cq    = (ushort_t*)(sp + (size_t)4 * BB * TT * SS); // 1 MB ([ctx|q] bf16)

    hipMemsetAsync(d_ws, 0, 16384, stream);   // zero barrier counters/flags
    mega_kernel<<<dim3(NBLK), 256, 0, stream>>>(
        query, enc, lens, W_s, W_h, W_out, v, out, bar,
        WTs, WTh, WTo, encB, tqa, peT, sp, cq);
}

// Round 11
// 126.296 us; speedup vs baseline: 6.1798x; 6.1798x over previous
//
#include <hip/hip_runtime.h>
#include <math.h>

#define HD 512
#define BB 4
#define TT 128
#define SS 512

typedef __attribute__((ext_vector_type(8))) short short8;
typedef __attribute__((ext_vector_type(4))) float floatx4;
typedef _Float16 half2_t __attribute__((ext_vector_type(2)));
typedef unsigned short ushort_t;
typedef unsigned int uint_t;

__device__ __forceinline__ float tanh_e(float x) {
    float t = __builtin_amdgcn_rcpf(__expf(2.f * x) + 1.f);
    return fmaf(-2.f, t, 1.f);
}
__device__ __forceinline__ ushort_t f2bf(float x) {      // RNE fp32->bf16
    unsigned int u = __float_as_uint(x);
    u += 0x7fffu + ((u >> 16) & 1u);
    return (ushort_t)(u >> 16);
}

// ---- Kernel 0: prep. W->bf16 [n][k] transposed (coalesced); query->cq right; enc->bf16 ----
__global__ __launch_bounds__(256) void wtrans_kernel(
    const float* __restrict__ Ws, const float* __restrict__ Wh,
    const float* __restrict__ Wo, const float* __restrict__ query,
    const float* __restrict__ enc,
    ushort_t* __restrict__ Ts, ushort_t* __restrict__ Th, ushort_t* __restrict__ To,
    ushort_t* __restrict__ cq, ushort_t* __restrict__ encB)
{
    const int bid = blockIdx.x;
    const int tid = threadIdx.x;
    if (bid < 128) {
        const float* src; ushort_t* dst; int K, l;
        if (bid < 32)      { src = Ws; dst = Ts; K = 512;  l = bid;      }
        else if (bid < 64) { src = Wh; dst = Th; K = 512;  l = bid - 32; }
        else               { src = Wo; dst = To; K = 1024; l = bid - 64; }
        const int ktiles = K >> 7;
        const int tk = l & (ktiles - 1), tn = l / ktiles;
        const int k0 = tk * 128, n0 = tn * 64;

        __shared__ ushort_t tile[64][136];     // [n][k], row 272B

        const int lr  = tid >> 4;              // 0..15
        const int lc4 = (tid & 15) * 4;        // 0..60
        #pragma unroll
        for (int p = 0; p < 8; ++p) {
            const int row = p * 16 + lr;       // k-local
            float4 s = *(const float4*)(src + (size_t)(k0 + row) * HD + n0 + lc4);
            tile[lc4 + 0][row] = f2bf(s.x);
            tile[lc4 + 1][row] = f2bf(s.y);
            tile[lc4 + 2][row] = f2bf(s.z);
            tile[lc4 + 3][row] = f2bf(s.w);
        }
        __syncthreads();
        const int n = tid >> 2, kc = (tid & 3) * 32;
        #pragma unroll
        for (int j = 0; j < 4; ++j) {
            uint4 o = *(const uint4*)&tile[n][kc + j * 8];
            *(uint4*)&dst[(size_t)(n0 + n) * K + k0 + kc + j * 8] = o;
        }
    } else if (bid < 256) {
        // query -> bf16 into cq[m][512 + h]
        const int idx = ((bid - 128) * 256 + tid) * 8;
        const int m = idx >> 9, h = idx & 511;
        float4 q0 = *(const float4*)(query + (size_t)m * HD + h);
        float4 q1 = *(const float4*)(query + (size_t)m * HD + h + 4);
        uint4 o;
        o.x = (uint_t)f2bf(q0.x) | ((uint_t)f2bf(q0.y) << 16);
        o.y = (uint_t)f2bf(q0.z) | ((uint_t)f2bf(q0.w) << 16);
        o.z = (uint_t)f2bf(q1.x) | ((uint_t)f2bf(q1.y) << 16);
        o.w = (uint_t)f2bf(q1.z) | ((uint_t)f2bf(q1.w) << 16);
        *(uint4*)&cq[(size_t)m * 1024 + 512 + h] = o;
    } else {
        // enc -> bf16 encB (row-major)
        const size_t idx = ((size_t)(bid - 256) * 256 + tid) * 8;
        float4 e0 = *(const float4*)(enc + idx);
        float4 e1 = *(const float4*)(enc + idx + 4);
        uint4 o;
        o.x = (uint_t)f2bf(e0.x) | ((uint_t)f2bf(e0.y) << 16);
        o.y = (uint_t)f2bf(e0.z) | ((uint_t)f2bf(e0.w) << 16);
        o.z = (uint_t)f2bf(e1.x) | ((uint_t)f2bf(e1.y) << 16);
        o.w = (uint_t)f2bf(e1.z) | ((uint_t)f2bf(e1.w) << 16);
        *(uint4*)&encB[idx] = o;
    }
}

// ---- Kernel 1: MFMA proj. q-path: tqa = {tanh(pq), v*tanh(pq)} fp32.
//                           enc-path: peT = fp16(tanh(pe))^T per batch (B,H,S). ----
#define LDP 40
__global__ __launch_bounds__(256) void proj_kernel(
    const ushort_t* __restrict__ cq, const ushort_t* __restrict__ encB,
    const ushort_t* __restrict__ WTs, const ushort_t* __restrict__ WTh,
    const float* __restrict__ v,
    float2* __restrict__ tqa, _Float16* __restrict__ peT)
{
    const int bm = blockIdx.x;            // 0..39: 8 query tiles, 32 enc tiles
    const int bn = blockIdx.y;            // 0..7
    const bool isQ = (bm < 8);
    const ushort_t* A = isQ ? (cq + 512) : encB;
    const int lda = isQ ? 1024 : 512;
    const ushort_t* WT = isQ ? WTs : WTh;
    const int m0 = (isQ ? bm : bm - 8) * 64;
    const int n0 = bn * 64;

    __shared__ ushort_t As[64 * LDP];     // [m][k]
    __shared__ ushort_t Bs[64 * LDP];     // [n][k]

    const int tid = threadIdx.x;
    const int lane = tid & 63, w = tid >> 6;
    const int quad = lane >> 4, lrow = lane & 15;
    const int mw = (w & 1) * 32, nw = (w >> 1) * 32;

    const int ar = tid >> 2;              // 0..63
    const int ac = (tid & 3) * 8;         // 0,8,16,24

    floatx4 zero = {0.f, 0.f, 0.f, 0.f};
    floatx4 acc[2][2] = {{zero, zero}, {zero, zero}};

    uint4 ald = *(const uint4*)&A[(size_t)(m0 + ar) * lda + ac];
    uint4 bld = *(const uint4*)&WT[(size_t)(n0 + ar) * HD + ac];

    for (int k0 = 0; k0 < HD; k0 += 32) {
        __syncthreads();
        *(uint4*)&As[ar * LDP + ac] = ald;
        *(uint4*)&Bs[ar * LDP + ac] = bld;
        __syncthreads();
        if (k0 + 32 < HD) {
            ald = *(const uint4*)&A[(size_t)(m0 + ar) * lda + k0 + 32 + ac];
            bld = *(const uint4*)&WT[(size_t)(n0 + ar) * HD + k0 + 32 + ac];
        }
        short8 af[2], bf[2];
        #pragma unroll
        for (int i = 0; i < 2; ++i)
            af[i] = *(const short8*)&As[(mw + i * 16 + lrow) * LDP + quad * 8];
        #pragma unroll
        for (int j = 0; j < 2; ++j)
            bf[j] = *(const short8*)&Bs[(nw + j * 16 + lrow) * LDP + quad * 8];
        #pragma unroll
        for (int i = 0; i < 2; ++i)
            #pragma unroll
            for (int j = 0; j < 2; ++j)
                acc[i][j] = __builtin_amdgcn_mfma_f32_16x16x32_bf16(af[i], bf[j], acc[i][j], 0, 0, 0);
    }

    if (isQ) {
        #pragma unroll
        for (int j = 0; j < 2; ++j) {
            const int col = n0 + nw + j * 16 + lrow;
            const float vj = v[col];
            #pragma unroll
            for (int i = 0; i < 2; ++i)
                #pragma unroll
                for (int r = 0; r < 4; ++r) {
                    const int row = m0 + mw + i * 16 + quad * 4 + r;
                    float tq = tanh_e(acc[i][j][r]);
                    float2 o; o.x = tq; o.y = vj * tq;
                    tqa[(size_t)row * HD + col] = o;
                }
        }
    } else {
        #pragma unroll
        for (int i = 0; i < 2; ++i)
            #pragma unroll
            for (int j = 0; j < 2; ++j) {
                const int gm = m0 + mw + i * 16 + quad * 4;
                const int b = gm >> 9, s = gm & 511;
                const int col = n0 + nw + j * 16 + lrow;
                _Float16 t0 = (_Float16)tanh_e(acc[i][j][0]);
                _Float16 t1 = (_Float16)tanh_e(acc[i][j][1]);
                _Float16 t2 = (_Float16)tanh_e(acc[i][j][2]);
                _Float16 t3 = (_Float16)tanh_e(acc[i][j][3]);
                ushort4 o;
                o.x = *(ushort_t*)&t0; o.y = *(ushort_t*)&t1;
                o.z = *(ushort_t*)&t2; o.w = *(ushort_t*)&t3;
                *(ushort4*)((ushort_t*)peT + ((size_t)b * HD + col) * SS + s) = o;
            }
    }
}

// ---- Kernel 2: partial scores, tanh addition formula, paired-rcp.
//      grid (B*T, 4), 128 thr x 4 s.  term = v*(Tq+Te)/(1+Tq*Te). ----
__global__ __launch_bounds__(128) void score_part_kernel(
    const float2* __restrict__ tqa, const _Float16* __restrict__ peT,
    const float* __restrict__ vv, const int* __restrict__ lens,
    _Float16* __restrict__ sp)
{
    const int bt = blockIdx.x;
    const int hq = blockIdx.y;
    const int b = bt >> 7;
    const int tid = threadIdx.x;
    const int h0 = hq * 128;

    const int len = lens[b];
    const int s0 = tid * 4;
    if (s0 >= len) return;

    const float2* qa = tqa + (size_t)bt * HD + h0;       // wave-uniform -> SGPR
    const float* vp = vv + h0;                           // wave-uniform -> SGPR
    const ushort_t* col = (const ushort_t*)peT + ((size_t)b * HD + h0) * SS + s0;

    float acc[4] = {0.f, 0.f, 0.f, 0.f};
    #pragma unroll 4
    for (int h = 0; h < 128; h += 2) {
        uint2 pA = *(const uint2*)(col + (size_t)h * SS);
        uint2 pB = *(const uint2*)(col + (size_t)(h + 1) * SS);
        const float2 qA = qa[h], qB = qa[h + 1];
        const float vA = vp[h], vB = vp[h + 1];
        half2_t a01 = *(half2_t*)&pA.x, a23 = *(half2_t*)&pA.y;
        half2_t b01 = *(half2_t*)&pB.x, b23 = *(half2_t*)&pB.y;
        float teA[4] = {(float)a01[0], (float)a01[1], (float)a23[0], (float)a23[1]};
        float teB[4] = {(float)b01[0], (float)b01[1], (float)b23[0], (float)b23[1]};
        #pragma unroll
        for (int s = 0; s < 4; ++s) {
            float dA = fmaf(qA.x, teA[s], 1.f);
            float dB = fmaf(qB.x, teB[s], 1.f);
            float mA = fmaf(vA, teA[s], qA.y);
            float mB = fmaf(vB, teB[s], qB.y);
            float num = mA * dB;
            num = fmaf(mB, dA, num);
            acc[s] = fmaf(num, __builtin_amdgcn_rcpf(dA * dB), acc[s]);
        }
    }
    _Float16 f0 = (_Float16)acc[0], f1 = (_Float16)acc[1];
    _Float16 f2 = (_Float16)acc[2], f3 = (_Float16)acc[3];
    uint2 pk;
    pk.x = (uint_t)*(ushort_t*)&f0 | ((uint_t)*(ushort_t*)&f1 << 16);
    pk.y = (uint_t)*(ushort_t*)&f2 | ((uint_t)*(ushort_t*)&f3 << 16);
    *(uint2*)(sp + ((size_t)hq * (BB * TT) + bt) * SS + s0) = pk;
}

// ---- Kernel 3: combine partials + masked softmax -> alpha (zeros past len) ----
__global__ __launch_bounds__(512) void combine_kernel(
    const _Float16* __restrict__ sp, const int* __restrict__ lens,
    float* __restrict__ alpha)
{
    const int bt = blockIdx.x;
    const int b = bt >> 7;
    const int tid = threadIdx.x;
    const int wave = tid >> 6;
    __shared__ float s_red[16];

    const int len = lens[b];
    float sc = -INFINITY;
    if (tid < len) {
        const size_t i = (size_t)bt * SS + tid;
        const size_t st = (size_t)BB * TT * SS;
        sc = (float)sp[i] + (float)sp[i + st] + (float)sp[i + 2 * st] + (float)sp[i + 3 * st];
    }
    float m = sc;
    #pragma unroll
    for (int off = 32; off; off >>= 1) m = fmaxf(m, __shfl_xor(m, off, 64));
    if ((tid & 63) == 0) s_red[wave] = m;
    __syncthreads();
    m = s_red[0];
    #pragma unroll
    for (int w2 = 1; w2 < 8; ++w2) m = fmaxf(m, s_red[w2]);

    float e = (tid < len) ? __expf(sc - m) : 0.f;
    float sum = e;
    #pragma unroll
    for (int off = 32; off; off >>= 1) sum += __shfl_xor(sum, off, 64);
    if ((tid & 63) == 0) s_red[8 + wave] = sum;
    __syncthreads();
    float total = s_red[8];
    #pragma unroll
    for (int w2 = 1; w2 < 8; ++w2) total += s_red[8 + w2];

    alpha[(size_t)bt * SS + tid] = e * __builtin_amdgcn_rcpf(total);
}

// ---- Kernel 4: ctx = alpha @ enc via MFMA, bf16 out into cq[:, 0:512] ----
#define LDA_A 40
#define LDA_B 76
__global__ __launch_bounds__(256) void ctx_kernel(
    const float* __restrict__ alpha, const ushort_t* __restrict__ encB,
    const int* __restrict__ lens, ushort_t* __restrict__ cq)
{
    const int b = blockIdx.x;
    const int t0 = blockIdx.y * 16;
    const int h0 = blockIdx.z * 64;
    __shared__ ushort_t sA[16 * LDA_A];   // [t][s]
    __shared__ ushort_t sB[32 * LDA_B];   // [s][h]
    const int tid = threadIdx.x;
    const int lane = tid & 63, w = tid >> 6;
    const int quad = lane >> 4, lrow = lane & 15;
    const int nw = w * 16;
    const int len = lens[b];

    const int ar  = tid >> 4;          // 0..15  (t)
    const int ac2 = (tid & 15) * 2;    // 0..30  (s pair)
    const int br  = tid >> 3;          // 0..31  (s)
    const int bc8 = (tid & 7) * 8;     // h offset

    floatx4 acc = {0.f, 0.f, 0.f, 0.f};

    for (int s0 = 0; s0 < len; s0 += 32) {
        __syncthreads();
        {
            float2 a2 = *(const float2*)(alpha + (size_t)(b * TT + t0 + ar) * SS + s0 + ac2);
            uint_t pk = (uint_t)f2bf(a2.x) | ((uint_t)f2bf(a2.y) << 16);
            *(uint_t*)&sA[ar * LDA_A + ac2] = pk;
            uint4 ev = *(const uint4*)&encB[(size_t)(b * SS + s0 + br) * HD + h0 + bc8];
            *(uint4*)&sB[br * LDA_B + bc8] = ev;
        }
        __syncthreads();
        short8 af = *(const short8*)&sA[lrow * LDA_A + quad * 8];
        short8 bf;
        #pragma unroll
        for (int j = 0; j < 8; ++j)
            bf[j] = (short)sB[(quad * 8 + j) * LDA_B + nw + lrow];
        acc = __builtin_amdgcn_mfma_f32_16x16x32_bf16(af, bf, acc, 0, 0, 0);
    }
    #pragma unroll
    for (int r = 0; r < 4; ++r)
        cq[(size_t)(b * TT + t0 + quad * 4 + r) * 1024 + h0 + nw + lrow] = f2bf(acc[r]);
}

// ---- Kernel 5: out = tanh(cq @ WTo^T), MFMA, 32x32 tiles, 256 blocks ----
__global__ __launch_bounds__(256) void out_kernel(
    const ushort_t* __restrict__ cq, const ushort_t* __restrict__ WTo,
    float* __restrict__ out)
{
    const int m0 = blockIdx.x * 32;
    const int n0 = blockIdx.y * 32;

    __shared__ ushort_t As[32 * LDP];     // [m][k]
    __shared__ ushort_t Bs[32 * LDP];     // [n][k]

    const int tid = threadIdx.x;
    const int lane = tid & 63, w = tid >> 6;
    const int quad = lane >> 4, lrow = lane & 15;
    const int mw = (w & 1) * 16, nw = (w >> 1) * 16;

    const int r8 = tid >> 3, c4 = (tid & 7) * 4;

    floatx4 acc = {0.f, 0.f, 0.f, 0.f};

    uint2 av = *(const uint2*)&cq[(size_t)(m0 + r8) * 1024 + c4];
    uint2 bv = *(const uint2*)&WTo[(size_t)(n0 + r8) * 1024 + c4];

    for (int k0 = 0; k0 < 1024; k0 += 32) {
        __syncthreads();
        *(uint2*)&As[r8 * LDP + c4] = av;
        *(uint2*)&Bs[r8 * LDP + c4] = bv;
        __syncthreads();
        if (k0 + 32 < 1024) {
            av = *(const uint2*)&cq[(size_t)(m0 + r8) * 1024 + k0 + 32 + c4];
            bv = *(const uint2*)&WTo[(size_t)(n0 + r8) * 1024 + k0 + 32 + c4];
        }
        short8 af = *(const short8*)&As[(mw + lrow) * LDP + quad * 8];
        short8 bf = *(const short8*)&Bs[(nw + lrow) * LDP + quad * 8];
        acc = __builtin_amdgcn_mfma_f32_16x16x32_bf16(af, bf, acc, 0, 0, 0);
    }
    #pragma unroll
    for (int r = 0; r < 4; ++r) {
        const int row = m0 + mw + quad * 4 + r;
        const int col = n0 + nw + lrow;
        out[(size_t)row * HD + col] = tanh_e(acc[r]);
    }
}

extern "C" void kernel_launch(void* const* d_in, const int* in_sizes, int n_in,
                              void* d_out, int out_size, void* d_ws, size_t ws_size,
                              hipStream_t stream) {
    (void)in_sizes; (void)n_in; (void)out_size; (void)ws_size;
    const float* query = (const float*)d_in[0];   // (B,T,H)
    const float* enc   = (const float*)d_in[1];   // (B,S,H)
    const int*   lens  = (const int*)d_in[2];     // (B,)
    const float* W_h   = (const float*)d_in[3];   // (H,H)
    const float* W_s   = (const float*)d_in[4];   // (H,H)
    const float* v     = (const float*)d_in[5];   // (H,)
    const float* W_out = (const float*)d_in[6];   // (2H,H)
    float* out = (float*)d_out;

    // workspace layout (~12 MB)
    ushort_t* WTs   = (ushort_t*)d_ws;                          // 512 KB
    ushort_t* WTh   = WTs + (size_t)HD * HD;                    // 512 KB
    ushort_t* WTo   = WTh + (size_t)HD * HD;                    // 1 MB
    ushort_t* encB  = WTo + (size_t)HD * 2 * HD;                // 2 MB (bf16 enc)
    float2*   tqa   = (float2*)(encB + (size_t)BB * SS * HD);   // 2 MB {tanh(pq), v*tanh(pq)}
    _Float16* peT   = (_Float16*)(tqa + (size_t)BB * TT * HD);  // 2 MB fp16 tanh(pe)^T
    _Float16* sp    = peT + (size_t)BB * HD * SS;               // 2 MB fp16 partials
    float*    alpha = (float*)(sp + (size_t)4 * BB * TT * SS);  // 1 MB
    ushort_t* cq    = (ushort_t*)(alpha + (size_t)BB * TT * SS);// 1 MB ([ctx|q] bf16)

    wtrans_kernel<<<dim3(768), 256, 0, stream>>>(W_s, W_h, W_out, query, enc,
                                                 WTs, WTh, WTo, cq, encB);
    proj_kernel<<<dim3(40, 8), 256, 0, stream>>>(cq, encB, WTs, WTh, v, tqa, peT);
    score_part_kernel<<<dim3(BB * TT, 4), 128, 0, stream>>>(tqa, peT, v, lens, sp);
    combine_kernel<<<dim3(BB * TT), 512, 0, stream>>>(sp, lens, alpha);
    ctx_kernel<<<dim3(BB, TT / 16, HD / 64), 256, 0, stream>>>(alpha, encB, lens, cq);
    out_kernel<<<dim3(16, 16), 256, 0, stream>>>(cq, WTo, out);
}